// Round 10
// baseline (1805.810 us; speedup 1.0000x reference)
//
#include <hip/hip_runtime.h>
#include <hip/hip_cooperative_groups.h>

namespace cg = cooperative_groups;

#define NROWS 131072
#define DIM   128
#define FFD   512
#define TSTEPS 4
#define NSLOT 16
#define SH    136  // stride for 128-wide bf16 LDS tiles (16B-aligned rows)

typedef short          s8v   __attribute__((ext_vector_type(8)));
typedef float          f4v   __attribute__((ext_vector_type(4)));
typedef unsigned short u16x4 __attribute__((ext_vector_type(4)));

#define MFMA16(a,b,c) __builtin_amdgcn_mfma_f32_16x16x32_bf16((a),(b),(c),0,0,0)

__device__ __forceinline__ unsigned short f2bf(float f){
    unsigned u = __builtin_bit_cast(unsigned, f);
    u += 0x7FFFu + ((u >> 16) & 1u);   // round-to-nearest-even
    return (unsigned short)(u >> 16);
}
__device__ __forceinline__ float bf2f(unsigned short h){
    return __builtin_bit_cast(float, (unsigned)h << 16);
}
__device__ __forceinline__ f4v ntload4(const float* p){
    return __builtin_nontemporal_load((const f4v*)p);
}
__device__ __forceinline__ void ntstore4(float* p, f4v v){
    __builtin_nontemporal_store(v, (f4v*)p);
}

// Per-lane LN (optional) + bf16 split of one register-resident 128-wide row.
// DO_LN: apply layernorm with ga/be.  DO_LO: also write the low-order split.
template<bool DO_LN, bool DO_LO>
__device__ __forceinline__ void row_split(const f4v* xr, int rowoff,
                                          const float* __restrict__ ga,
                                          const float* __restrict__ be,
                                          unsigned short* hs_, unsigned short* hl_)
{
    float m = 0.f, rs = 1.f;
    if constexpr (DO_LN) {
        float s = 0.f, q = 0.f;
        #pragma unroll
        for (int j = 0; j < 32; ++j) {
            const f4v v = xr[j];
            s += v[0] + v[1] + v[2] + v[3];
            q += v[0]*v[0] + v[1]*v[1] + v[2]*v[2] + v[3]*v[3];
        }
        m  = s * (1.0f/128.0f);
        rs = rsqrtf(q * (1.0f/128.0f) - m*m + 1e-5f);
    }
    #pragma unroll
    for (int g2 = 0; g2 < 8; ++g2) {
        unsigned short hi16[16], lo16[16];
        #pragma unroll
        for (int jj = 0; jj < 4; ++jj) {
            const f4v v = xr[g2*4 + jj];
            f4v gg, bb;
            if constexpr (DO_LN) {
                gg = *(const f4v*)(ga + g2*16 + jj*4);
                bb = *(const f4v*)(be + g2*16 + jj*4);
            }
            #pragma unroll
            for (int e = 0; e < 4; ++e) {
                float hv;
                if constexpr (DO_LN) hv = (v[e] - m)*rs*gg[e] + bb[e];
                else                 hv = v[e];
                const unsigned short h = f2bf(hv);
                hi16[jj*4 + e] = h;
                if constexpr (DO_LO) lo16[jj*4 + e] = f2bf(hv - bf2f(h));
            }
        }
        *(s8v*)&hs_[rowoff + g2*16]     = *(const s8v*)&hi16[0];
        *(s8v*)&hs_[rowoff + g2*16 + 8] = *(const s8v*)&hi16[8];
        if constexpr (DO_LO) {
            *(s8v*)&hl_[rowoff + g2*16]     = *(const s8v*)&lo16[0];
            *(s8v*)&hl_[rowoff + g2*16 + 8] = *(const s8v*)&lo16[8];
        }
    }
}

// ---------------------------------------------------------------------------
// Persistent cooperative kernel: all 4 timesteps + final projection.
// 256 blocks x 512 threads, 1 block/CU. Thread t holds row (b*512+t) of x in
// 32 f4v registers across the whole kernel. Per timestep:
//   pass1: per-lane LN1 -> K/V proj -> KtV partials -> slot atomics
//   grid.sync ; blocks 0..31: reduce slots -> M = Qw@KtV (bf16 split) ; re-zero
//   grid.sync ; pass2: GEMM1 + LN2 + FF, updating x in registers.
// x touches HBM twice total (initial load, final O-proj store).
// ---------------------------------------------------------------------------
__global__ __launch_bounds__(512, 2)
void kMega(const float* __restrict__ x_in,
           const unsigned short* __restrict__ Kwp, const unsigned short* __restrict__ Vwp,
           const float* __restrict__ Qw,
           const float* __restrict__ g1a, const float* __restrict__ b1a,
           const float* __restrict__ g2a, const float* __restrict__ b2a,
           const unsigned short* __restrict__ w1p, const float* __restrict__ fb1,
           const unsigned short* __restrict__ w2p, const float* __restrict__ fb2,
           const unsigned short* __restrict__ Owp, const float* __restrict__ ob,
           float* __restrict__ slots, unsigned short* __restrict__ Mp,
           unsigned short* __restrict__ Ml, float* __restrict__ out)
{
    __shared__ __align__(16) char lraw[139264];
    unsigned short* const hs   = (unsigned short*)lraw;            // 34816 B
    unsigned short* const hl   = (unsigned short*)(lraw + 34816);  // 34816 B
    unsigned short* const fbuf = hl;                               // FF reuse
    unsigned short* const KT   = (unsigned short*)(lraw + 69632);  // pass1
    unsigned short* const VT   = (unsigned short*)(lraw + 104448); // pass1
    float*          const xb   = (float*)(lraw + 69632);           // pass2/staging (67584 B)
    float*          const colbuf = (float*)(lraw + 69632);         // buildM scratch

    const int tid  = threadIdx.x;
    const int wv   = tid >> 6, lane = tid & 63;
    const int quad = lane >> 4, l15 = lane & 15;
    const int myTile = tid >> 7, myRow = tid & 127;  // row ownership
    const int cgc  = wv*16 + l15;                    // GEMM col / proj col
    const int b    = blockIdx.x;
    const int rowoff = myRow * SH;

    cg::grid_group grid = cg::this_grid();

    // ---- preload x into registers: thread t owns row b*512 + t ----
    f4v xr[32];
    for (int p = 0; p < 4; ++p) {
        const size_t r0 = (size_t)b*512 + (size_t)p*128;
        #pragma unroll
        for (int i = 0; i < 8; ++i) {
            const int idx = tid + i*512;
            const int r = idx >> 5, c = (idx & 31)*4;
            *(f4v*)&xb[r*132 + c] = ntload4(x_in + (r0 + r)*DIM + c);
        }
        __syncthreads();
        if (myTile == p) {
            #pragma unroll
            for (int j = 0; j < 32; ++j) xr[j] = *(const f4v*)&xb[myRow*132 + j*4];
        }
        __syncthreads();
    }

    // K/V weight fragments: L2-hot, loaded once
    s8v bfK[4], bfV[4];
    #pragma unroll
    for (int ks = 0; ks < 4; ++ks) {
        bfK[ks] = *(const s8v*)(Kwp + cgc*DIM + ks*32 + quad*8);
        bfV[ks] = *(const s8v*)(Vwp + cgc*DIM + ks*32 + quad*8);
    }

    for (int ts = 0; ts < TSTEPS; ++ts) {
        // ================= pass 1: partial KtV over own 512 rows =================
        {
            f4v acc[8];
            #pragma unroll
            for (int i = 0; i < 8; ++i) acc[i] = (f4v){0.f,0.f,0.f,0.f};
            for (int p = 0; p < 4; ++p) {
                if (myTile == p)
                    row_split<true, true>(xr, rowoff, g1a, b1a, hs, hl);
                __syncthreads();
                #pragma unroll
                for (int pv = 0; pv < 2; ++pv) {
                    const s8v* bf = pv ? bfV : bfK;
                    unsigned short* T = pv ? VT : KT;
                    #pragma unroll
                    for (int mt = 0; mt < 8; ++mt) {
                        s8v ah[4], al[4];
                        #pragma unroll
                        for (int ks = 0; ks < 4; ++ks) {
                            ah[ks] = *(const s8v*)(&hs[(mt*16 + l15)*SH + ks*32 + quad*8]);
                            al[ks] = *(const s8v*)(&hl[(mt*16 + l15)*SH + ks*32 + quad*8]);
                        }
                        f4v c = {0.f,0.f,0.f,0.f};
                        #pragma unroll
                        for (int ks = 0; ks < 4; ++ks) c = MFMA16(ah[ks], bf[ks], c);
                        #pragma unroll
                        for (int ks = 0; ks < 4; ++ks) c = MFMA16(al[ks], bf[ks], c);
                        // C layout row=quad*4+reg col=l15 -> store transposed
                        u16x4 w4 = { f2bf(c[0]), f2bf(c[1]), f2bf(c[2]), f2bf(c[3]) };
                        *(u16x4*)&T[cgc*SH + mt*16 + quad*4] = w4;
                    }
                }
                __syncthreads();
                #pragma unroll
                for (int ks = 0; ks < 4; ++ks) {
                    const s8v af = *(const s8v*)(&KT[cgc*SH + ks*32 + quad*8]);
                    #pragma unroll
                    for (int jt = 0; jt < 8; ++jt) {
                        const s8v bfr = *(const s8v*)(&VT[(jt*16 + l15)*SH + ks*32 + quad*8]);
                        acc[jt] = MFMA16(af, bfr, acc[jt]);
                    }
                }
                __syncthreads();
            }
            float* S = slots + (size_t)(b & (NSLOT-1)) * 16384;
            #pragma unroll
            for (int jt = 0; jt < 8; ++jt) {
                const int i0 = wv*16 + quad*4;
                const int j  = jt*16 + l15;
                #pragma unroll
                for (int rg = 0; rg < 4; ++rg)
                    atomicAdd(&S[(i0 + rg)*DIM + j], acc[jt][rg]);
            }
        }
        __threadfence();
        grid.sync();
        // ========== reduce + buildM (blocks 0..31); re-zero slots ==========
        if (b < 32) {
            const int jj = tid >> 7;         // 0..3
            const int ii = tid & 127;        // 0..127
            const int j  = b*4 + jj;         // ktv column (0..127)
            float s = 0.f;
            for (int sl = 0; sl < NSLOT; ++sl) {
                float* ptr = slots + (size_t)sl*16384 + ii*128 + j;
                s += *ptr;
                *ptr = 0.f;                  // ready for next timestep
            }
            colbuf[jj*128 + ii] = s;
            __syncthreads();
            const int k = ii;
            float a2 = 0.f;
            for (int i = 0; i < 128; ++i) a2 += Qw[k*128 + i] * colbuf[jj*128 + i];
            const unsigned short hi = f2bf(a2);
            Mp[j*128 + k] = hi;
            Ml[j*128 + k] = f2bf(a2 - bf2f(hi));
            __syncthreads();
        }
        __threadfence();
        grid.sync();
        // ================= pass 2: transformer update =================
        {
            s8v bh[4], bl[4];
            #pragma unroll
            for (int ks = 0; ks < 4; ++ks) {
                bh[ks] = *(const s8v*)(Mp + cgc*DIM + ks*32 + quad*8);
                bl[ks] = *(const s8v*)(Ml + cgc*DIM + ks*32 + quad*8);
            }
            for (int p = 0; p < 4; ++p) {
                if (myTile == p) {
                    #pragma unroll
                    for (int j = 0; j < 32; ++j) *(f4v*)&xb[myRow*132 + j*4] = xr[j];
                    row_split<true, true>(xr, rowoff, g1a, b1a, hs, hl);
                }
                __syncthreads();
                // GEMM1: xb += h1 @ M (3-way split)
                #pragma unroll
                for (int mt = 0; mt < 8; ++mt) {
                    s8v ah[4], al[4];
                    #pragma unroll
                    for (int ks = 0; ks < 4; ++ks) {
                        ah[ks] = *(const s8v*)(&hs[(mt*16 + l15)*SH + ks*32 + quad*8]);
                        al[ks] = *(const s8v*)(&hl[(mt*16 + l15)*SH + ks*32 + quad*8]);
                    }
                    f4v c = {0.f,0.f,0.f,0.f};
                    #pragma unroll
                    for (int ks = 0; ks < 4; ++ks) c = MFMA16(ah[ks], bh[ks], c);
                    #pragma unroll
                    for (int ks = 0; ks < 4; ++ks) c = MFMA16(ah[ks], bl[ks], c);
                    #pragma unroll
                    for (int ks = 0; ks < 4; ++ks) c = MFMA16(al[ks], bh[ks], c);
                    #pragma unroll
                    for (int rg = 0; rg < 4; ++rg)
                        xb[(mt*16 + quad*4 + rg)*132 + cgc] += c[rg];
                }
                __syncthreads();
                if (myTile == p) {
                    #pragma unroll
                    for (int j = 0; j < 32; ++j) xr[j] = *(const f4v*)&xb[myRow*132 + j*4];
                    row_split<true, false>(xr, rowoff, g2a, b2a, hs, nullptr);
                }
                __syncthreads();
                // FF: 4 quarters
                f4v dx2[8];
                #pragma unroll
                for (int i = 0; i < 8; ++i) dx2[i] = (f4v){0.f,0.f,0.f,0.f};
                #pragma unroll
                for (int qf = 0; qf < 4; ++qf) {
                    s8v wa[4];
                    #pragma unroll
                    for (int ks = 0; ks < 4; ++ks)
                        wa[ks] = *(const s8v*)(w1p + (qf*128 + cgc)*DIM + ks*32 + quad*8);
                    const float bias = fb1[qf*128 + cgc];
                    #pragma unroll
                    for (int mt = 0; mt < 8; ++mt) {
                        s8v af[4];
                        #pragma unroll
                        for (int ks = 0; ks < 4; ++ks)
                            af[ks] = *(const s8v*)(&hs[(mt*16 + l15)*SH + ks*32 + quad*8]);
                        f4v c = {0.f,0.f,0.f,0.f};
                        #pragma unroll
                        for (int ks = 0; ks < 4; ++ks) c = MFMA16(af[ks], wa[ks], c);
                        #pragma unroll
                        for (int rg = 0; rg < 4; ++rg) {
                            float vv = c[rg] + bias;
                            vv = vv > 0.f ? vv : 0.f;
                            fbuf[(mt*16 + quad*4 + rg)*SH + cgc] = f2bf(vv);
                        }
                    }
                    __syncthreads();
                    s8v wb[4];
                    #pragma unroll
                    for (int ks = 0; ks < 4; ++ks)
                        wb[ks] = *(const s8v*)(w2p + cgc*FFD + qf*128 + ks*32 + quad*8);
                    #pragma unroll
                    for (int mt = 0; mt < 8; ++mt) {
                        s8v af[4];
                        #pragma unroll
                        for (int ks = 0; ks < 4; ++ks)
                            af[ks] = *(const s8v*)(&fbuf[(mt*16 + l15)*SH + ks*32 + quad*8]);
                        f4v c = dx2[mt];
                        #pragma unroll
                        for (int ks = 0; ks < 4; ++ks) c = MFMA16(af[ks], wb[ks], c);
                        dx2[mt] = c;
                    }
                    __syncthreads();
                }
                {
                    const float bias = fb2[cgc];
                    #pragma unroll
                    for (int mt = 0; mt < 8; ++mt)
                        #pragma unroll
                        for (int rg = 0; rg < 4; ++rg)
                            xb[(mt*16 + quad*4 + rg)*132 + cgc] += dx2[mt][rg] + bias;
                }
                __syncthreads();
                if (myTile == p) {
                    #pragma unroll
                    for (int j = 0; j < 32; ++j) xr[j] = *(const f4v*)&xb[myRow*132 + j*4];
                }
                __syncthreads();
            }
        }
    }
    // ================= final: out = x @ out_w + out_b =================
    {
        s8v bfO[4];
        #pragma unroll
        for (int ks = 0; ks < 4; ++ks)
            bfO[ks] = *(const s8v*)(Owp + cgc*DIM + ks*32 + quad*8);
        const float biasO = ob[cgc];
        for (int p = 0; p < 4; ++p) {
            if (myTile == p)
                row_split<false, true>(xr, rowoff, nullptr, nullptr, hs, hl);
            __syncthreads();
            #pragma unroll
            for (int mt = 0; mt < 8; ++mt) {
                s8v ah[4], al[4];
                #pragma unroll
                for (int ks = 0; ks < 4; ++ks) {
                    ah[ks] = *(const s8v*)(&hs[(mt*16 + l15)*SH + ks*32 + quad*8]);
                    al[ks] = *(const s8v*)(&hl[(mt*16 + l15)*SH + ks*32 + quad*8]);
                }
                f4v c = {0.f,0.f,0.f,0.f};
                #pragma unroll
                for (int ks = 0; ks < 4; ++ks) c = MFMA16(ah[ks], bfO[ks], c);
                #pragma unroll
                for (int ks = 0; ks < 4; ++ks) c = MFMA16(al[ks], bfO[ks], c);
                #pragma unroll
                for (int rg = 0; rg < 4; ++rg)
                    xb[(mt*16 + quad*4 + rg)*132 + cgc] = c[rg] + biasO;
            }
            __syncthreads();
            const size_t r0 = (size_t)b*512 + (size_t)p*128;
            #pragma unroll
            for (int i = 0; i < 8; ++i) {
                const int idx = tid + i*512;
                const int r = idx >> 5, c = (idx & 31)*4;
                ntstore4(out + (r0 + r)*DIM + c, *(const f4v*)&xb[r*132 + c]);
            }
            __syncthreads();
        }
    }
}

// Pack weights to bf16, transposed to B-operand-friendly [n][k] layout.
__global__ void kPack(const float* __restrict__ Kw, const float* __restrict__ Vw,
                      const float* __restrict__ Ow, const float* __restrict__ w1,
                      const float* __restrict__ w2,
                      unsigned short* __restrict__ Kwp, unsigned short* __restrict__ Vwp,
                      unsigned short* __restrict__ Owp, unsigned short* __restrict__ w1p,
                      unsigned short* __restrict__ w2p)
{
    const int t = blockIdx.x*256 + threadIdx.x;  // 147456 total
    if (t < 16384) {
        const int n = t >> 7, k = t & 127;
        Kwp[t] = f2bf(Kw[k*128 + n]);
        Vwp[t] = f2bf(Vw[k*128 + n]);
        Owp[t] = f2bf(Ow[k*128 + n]);
    } else if (t < 16384 + 65536) {
        const int u = t - 16384;
        const int n = u >> 7, k = u & 127;      // w1: [128][512] -> w1p[n<512][k<128]
        w1p[u] = f2bf(w1[k*FFD + n]);
    } else {
        const int u = t - 16384 - 65536;
        const int n = u >> 9, k = u & 511;      // w2: [512][128] -> w2p[n<128][k<511]
        w2p[u] = f2bf(w2[k*DIM + n]);
    }
}

extern "C" void kernel_launch(void* const* d_in, const int* in_sizes, int n_in,
                              void* d_out, int out_size, void* d_ws, size_t ws_size,
                              hipStream_t stream)
{
    (void)in_sizes; (void)n_in; (void)out_size; (void)ws_size;
    const float* x_in = (const float*)d_in[0];
    const float* Kw   = (const float*)d_in[1];
    const float* Qw   = (const float*)d_in[2];
    const float* Vw   = (const float*)d_in[3];
    const float* ln1g = (const float*)d_in[4];
    const float* ln1b = (const float*)d_in[5];
    const float* ln2g = (const float*)d_in[6];
    const float* ln2b = (const float*)d_in[7];
    const float* w1   = (const float*)d_in[8];
    const float* b1   = (const float*)d_in[9];
    const float* w2   = (const float*)d_in[10];
    const float* b2   = (const float*)d_in[11];
    const float* Ow   = (const float*)d_in[12];
    const float* ob   = (const float*)d_in[13];

    // Workspace (~1.4 MiB)
    char* p = (char*)d_ws;
    float* slots        = (float*)p;          p += (size_t)NSLOT*16384*4;
    unsigned short* Kwp = (unsigned short*)p; p += 16384*2;
    unsigned short* Vwp = (unsigned short*)p; p += 16384*2;
    unsigned short* Owp = (unsigned short*)p; p += 16384*2;
    unsigned short* w1p = (unsigned short*)p; p += 65536*2;
    unsigned short* w2p = (unsigned short*)p; p += 65536*2;
    unsigned short* Mp  = (unsigned short*)p; p += 16384*2;
    unsigned short* Ml  = (unsigned short*)p; p += 16384*2;

    float* out = (float*)d_out;

    kPack<<<576, 256, 0, stream>>>(Kw, Vw, Ow, w1, w2, Kwp, Vwp, Owp, w1p, w2p);
    (void)hipMemsetAsync(slots, 0, (size_t)NSLOT*16384*4, stream);

    void* args[] = {
        (void*)&x_in, (void*)&Kwp, (void*)&Vwp, (void*)&Qw,
        (void*)&ln1g, (void*)&ln1b, (void*)&ln2g, (void*)&ln2b,
        (void*)&w1p, (void*)&b1, (void*)&w2p, (void*)&b2,
        (void*)&Owp, (void*)&ob, (void*)&slots, (void*)&Mp,
        (void*)&Ml, (void*)&out
    };
    (void)hipLaunchCooperativeKernel((const void*)kMega, dim3(256), dim3(512),
                                     args, 0, stream);
}

// Round 11
// 1036.225 us; speedup vs baseline: 1.7427x; 1.7427x over previous
//
#include <hip/hip_runtime.h>

#define NROWS 131072
#define DIM   128
#define FFD   512
#define TSTEPS 4
#define NBLK  256
#define CHUNK 128
#define NCHUNK 4   // NROWS / (NBLK*CHUNK)
#define NSLOT 16
#define SH    136  // stride for 128-wide bf16 LDS tiles (16B-aligned rows)

static_assert((long)NBLK * CHUNK * NCHUNK == NROWS, "grid/chunk mismatch");

typedef short          s8v   __attribute__((ext_vector_type(8)));
typedef float          f4v   __attribute__((ext_vector_type(4)));
typedef unsigned short u16x4 __attribute__((ext_vector_type(4)));

#define MFMA16(a,b,c) __builtin_amdgcn_mfma_f32_16x16x32_bf16((a),(b),(c),0,0,0)
// Pin a value into registers: the asm "writes" it, so the compiler cannot
// rematerialize (re-load) it later. Zero instructions emitted.
#define PIN(x) asm volatile("" : "+v"(x))

__device__ __forceinline__ unsigned short f2bf(float f){
    unsigned u = __builtin_bit_cast(unsigned, f);
    u += 0x7FFFu + ((u >> 16) & 1u);   // round-to-nearest-even
    return (unsigned short)(u >> 16);
}
__device__ __forceinline__ float bf2f(unsigned short h){
    return __builtin_bit_cast(float, (unsigned)h << 16);
}
__device__ __forceinline__ f4v ntload4(const float* p){
    return __builtin_nontemporal_load((const f4v*)p);
}
__device__ __forceinline__ void ntstore4(float* p, f4v v){
    __builtin_nontemporal_store(v, (f4v*)p);
}

// ---------------------------------------------------------------------------
// Kernel A: LN1 (split bf16), K/V projections, per-block partial KtV -> slots.
// 256 blocks x 4 chunks of 128 rows; K/V weight fragments loaded once & pinned.
// ---------------------------------------------------------------------------
__global__ __launch_bounds__(512, 2)
void kA(const float* __restrict__ x, const unsigned short* __restrict__ Kwp,
        const unsigned short* __restrict__ Vwp,
        const float* __restrict__ ga, const float* __restrict__ be,
        float* __restrict__ slots)
{
    __shared__ unsigned short hh[128*SH];
    __shared__ unsigned short hl[128*SH];
    __shared__ unsigned short KT[128*SH];
    __shared__ unsigned short VT[128*SH];
    const int tid  = threadIdx.x;
    const int wv   = tid >> 6, lane = tid & 63;
    const int quad = lane >> 4, l15 = lane & 15;
    const int lp   = lane >> 3, lr = lane & 7;
    const int myrow = wv*8 + lr;
    const int pc    = wv*16 + l15;

    s8v bfK[4], bfV[4];
    #pragma unroll
    for (int ks = 0; ks < 4; ++ks) {
        bfK[ks] = *(const s8v*)(Kwp + pc*DIM + ks*32 + quad*8);
        bfV[ks] = *(const s8v*)(Vwp + pc*DIM + ks*32 + quad*8);
        PIN(bfK[ks]); PIN(bfV[ks]);
    }

    f4v acc[8];
    #pragma unroll
    for (int i = 0; i < 8; ++i) acc[i] = (f4v){0.f,0.f,0.f,0.f};

    for (int ch = 0; ch < NCHUNK; ++ch) {
        const size_t r0 = ((size_t)blockIdx.x*NCHUNK + ch)*CHUNK;
        #pragma unroll
        for (int pp = 0; pp < 2; ++pp) {
            const int row = pp*64 + myrow;
            float v[16];
            #pragma unroll
            for (int j = 0; j < 4; ++j) {
                const f4v t = ntload4(x + (r0 + row)*DIM + lp*16 + j*4);
                v[j*4+0] = t[0]; v[j*4+1] = t[1]; v[j*4+2] = t[2]; v[j*4+3] = t[3];
            }
            float s = 0.f, q = 0.f;
            #pragma unroll
            for (int i = 0; i < 16; ++i) { s += v[i]; q += v[i]*v[i]; }
            #pragma unroll
            for (int o = 8; o < 64; o <<= 1) { s += __shfl_xor(s, o); q += __shfl_xor(q, o); }
            const float m  = s * (1.0f/128.0f);
            const float rs = rsqrtf(q * (1.0f/128.0f) - m*m + 1e-5f);
            unsigned short hi16[16], lo16[16];
            #pragma unroll
            for (int j = 0; j < 4; ++j) {
                const float4 g = *(const float4*)(ga + lp*16 + j*4);
                const float4 b = *(const float4*)(be + lp*16 + j*4);
                float hv0 = (v[j*4+0]-m)*rs*g.x + b.x;
                float hv1 = (v[j*4+1]-m)*rs*g.y + b.y;
                float hv2 = (v[j*4+2]-m)*rs*g.z + b.z;
                float hv3 = (v[j*4+3]-m)*rs*g.w + b.w;
                hi16[j*4+0] = f2bf(hv0); lo16[j*4+0] = f2bf(hv0 - bf2f(hi16[j*4+0]));
                hi16[j*4+1] = f2bf(hv1); lo16[j*4+1] = f2bf(hv1 - bf2f(hi16[j*4+1]));
                hi16[j*4+2] = f2bf(hv2); lo16[j*4+2] = f2bf(hv2 - bf2f(hi16[j*4+2]));
                hi16[j*4+3] = f2bf(hv3); lo16[j*4+3] = f2bf(hv3 - bf2f(hi16[j*4+3]));
            }
            #pragma unroll
            for (int j = 0; j < 2; ++j) {
                *(s8v*)&hh[row*SH + lp*16 + j*8] = *(const s8v*)&hi16[j*8];
                *(s8v*)&hl[row*SH + lp*16 + j*8] = *(const s8v*)&lo16[j*8];
            }
        }
        __syncthreads();
        #pragma unroll
        for (int p = 0; p < 2; ++p) {
            const s8v* bf = p ? bfV : bfK;
            unsigned short* T = p ? VT : KT;
            #pragma unroll
            for (int mt = 0; mt < 8; ++mt) {
                s8v ah[4], al[4];
                #pragma unroll
                for (int ks = 0; ks < 4; ++ks) {
                    ah[ks] = *(const s8v*)(&hh[(mt*16 + l15)*SH + ks*32 + quad*8]);
                    al[ks] = *(const s8v*)(&hl[(mt*16 + l15)*SH + ks*32 + quad*8]);
                }
                f4v c = {0.f,0.f,0.f,0.f};
                #pragma unroll
                for (int ks = 0; ks < 4; ++ks) c = MFMA16(ah[ks], bf[ks], c);
                #pragma unroll
                for (int ks = 0; ks < 4; ++ks) c = MFMA16(al[ks], bf[ks], c);
                u16x4 w4 = { f2bf(c[0]), f2bf(c[1]), f2bf(c[2]), f2bf(c[3]) };
                *(u16x4*)&T[pc*SH + mt*16 + quad*4] = w4;
            }
        }
        __syncthreads();
        #pragma unroll
        for (int ks = 0; ks < 4; ++ks) {
            const s8v af = *(const s8v*)(&KT[pc*SH + ks*32 + quad*8]);
            #pragma unroll
            for (int jt = 0; jt < 8; ++jt) {
                const s8v bfr = *(const s8v*)(&VT[(jt*16 + l15)*SH + ks*32 + quad*8]);
                acc[jt] = MFMA16(af, bfr, acc[jt]);
            }
        }
        __syncthreads();
    }
    float* S = slots + (size_t)(blockIdx.x & (NSLOT-1)) * 16384;
    #pragma unroll
    for (int jt = 0; jt < 8; ++jt) {
        const int i0 = wv*16 + quad*4;
        const int j  = jt*16 + l15;
        #pragma unroll
        for (int rg = 0; rg < 4; ++rg)
            atomicAdd(&S[(i0 + rg)*DIM + j], acc[jt][rg]);
    }
}

// Reduce NSLOT partial KtV matrices -> ktv (fp32, 128x128)
__global__ void kReduce(const float* __restrict__ slots, float* __restrict__ ktv)
{
    const int e = blockIdx.x*256 + threadIdx.x;
    float s = 0.f;
    #pragma unroll
    for (int b = 0; b < NSLOT; ++b) s += slots[(size_t)b*16384 + e];
    ktv[e] = s;
}

// M = Qw @ KtV (fp32), packed split bf16 as Mp/Ml[j][k]
__global__ void kBuildM(const float* __restrict__ Qw, const float* __restrict__ ktv,
                        unsigned short* __restrict__ Mp, unsigned short* __restrict__ Ml)
{
    const int idx = blockIdx.x*256 + threadIdx.x;
    const int j = idx >> 7, k = idx & 127;
    float s = 0.f;
    for (int i = 0; i < 128; ++i) s += Qw[k*128 + i] * ktv[i*128 + j];
    const unsigned short hi = f2bf(s);
    Mp[idx] = hi;
    Ml[idx] = f2bf(s - bf2f(hi));
}

// ---------------------------------------------------------------------------
// Kernel B: x += h1 @ M ; LN2 ; x += relu(h2@w1+b1)@w2 + b2   (in-place safe)
// 256 blocks x 4 chunks of 128 rows. ALL weight fragments (M: bh/bl, FF:
// wa/wb) loaded once per block and PINNED in registers (asm) so the compiler
// cannot rematerialize the loads per chunk. ~240 VGPRs, 1 block/CU.
// ---------------------------------------------------------------------------
__global__ __launch_bounds__(512, 2)
void kB(const float* __restrict__ xin, float* __restrict__ xout,
        const unsigned short* __restrict__ Mp, const unsigned short* __restrict__ Ml,
        const float* __restrict__ g1a, const float* __restrict__ b1a,
        const float* __restrict__ g2a, const float* __restrict__ b2a,
        const unsigned short* __restrict__ w1p, const float* __restrict__ fb1,
        const unsigned short* __restrict__ w2p, const float* __restrict__ fb2)
{
    __shared__ float          xb[128*132];  // fp32 residual tile (67.6 KB)
    __shared__ unsigned short hs[128*SH];   // bf16 LN output hi   (34.8 KB)
    __shared__ unsigned short fbuf[128*SH]; // relu(ff) / h1-lo    (34.8 KB)
    unsigned short* const hl = fbuf;
    const int tid  = threadIdx.x;
    const int wv   = tid >> 6, lane = tid & 63;
    const int quad = lane >> 4, l15 = lane & 15;
    const int lp   = lane >> 3, lr = lane & 7;
    const int myrow = wv*8 + lr;
    const int cg    = wv*16 + l15;

    // --- hoisted + pinned fragments: loaded once per block ---
    s8v bh[4], bl[4];
    #pragma unroll
    for (int ks = 0; ks < 4; ++ks) {
        bh[ks] = *(const s8v*)(Mp + cg*DIM + ks*32 + quad*8);
        bl[ks] = *(const s8v*)(Ml + cg*DIM + ks*32 + quad*8);
        PIN(bh[ks]); PIN(bl[ks]);
    }
    s8v wa[4][4], wb[4][4];
    float b1r[4];
    #pragma unroll
    for (int qf = 0; qf < 4; ++qf) {
        const int ffc = qf*128 + cg;
        #pragma unroll
        for (int ks = 0; ks < 4; ++ks) {
            wa[qf][ks] = *(const s8v*)(w1p + ffc*DIM + ks*32 + quad*8);
            wb[qf][ks] = *(const s8v*)(w2p + cg*FFD + qf*128 + ks*32 + quad*8);
            PIN(wa[qf][ks]); PIN(wb[qf][ks]);
        }
        b1r[qf] = fb1[ffc];
    }

    for (int ch = 0; ch < NCHUNK; ++ch) {
        const size_t r0 = ((size_t)blockIdx.x*NCHUNK + ch)*CHUNK;
        // --- stage x chunk into LDS ---
        #pragma unroll
        for (int i = 0; i < 8; ++i) {
            const int idx = tid + i*512;
            const int r = idx >> 5, c = (idx & 31)*4;
            const f4v t = ntload4(xin + (r0 + r)*DIM + c);
            *(f4v*)&xb[r*132 + c] = t;
        }
        __syncthreads();
        // --- LN1 (split), 2 passes of 64 rows ---
        #pragma unroll
        for (int pp = 0; pp < 2; ++pp) {
            const int row = pp*64 + myrow;
            float v[16];
            #pragma unroll
            for (int j = 0; j < 4; ++j)
                *(float4*)&v[j*4] = *(const float4*)&xb[row*132 + lp*16 + j*4];
            float s = 0.f, q = 0.f;
            #pragma unroll
            for (int i = 0; i < 16; ++i) { s += v[i]; q += v[i]*v[i]; }
            #pragma unroll
            for (int o = 8; o < 64; o <<= 1) { s += __shfl_xor(s, o); q += __shfl_xor(q, o); }
            const float m  = s * (1.0f/128.0f);
            const float rs = rsqrtf(q * (1.0f/128.0f) - m*m + 1e-5f);
            unsigned short hi16[16], lo16[16];
            #pragma unroll
            for (int j = 0; j < 4; ++j) {
                const float4 g = *(const float4*)(g1a + lp*16 + j*4);
                const float4 b = *(const float4*)(b1a + lp*16 + j*4);
                float hv0 = (v[j*4+0]-m)*rs*g.x + b.x;
                float hv1 = (v[j*4+1]-m)*rs*g.y + b.y;
                float hv2 = (v[j*4+2]-m)*rs*g.z + b.z;
                float hv3 = (v[j*4+3]-m)*rs*g.w + b.w;
                hi16[j*4+0] = f2bf(hv0); lo16[j*4+0] = f2bf(hv0 - bf2f(hi16[j*4+0]));
                hi16[j*4+1] = f2bf(hv1); lo16[j*4+1] = f2bf(hv1 - bf2f(hi16[j*4+1]));
                hi16[j*4+2] = f2bf(hv2); lo16[j*4+2] = f2bf(hv2 - bf2f(hi16[j*4+2]));
                hi16[j*4+3] = f2bf(hv3); lo16[j*4+3] = f2bf(hv3 - bf2f(hi16[j*4+3]));
            }
            #pragma unroll
            for (int j = 0; j < 2; ++j) {
                *(s8v*)&hs[row*SH + lp*16 + j*8] = *(const s8v*)&hi16[j*8];
                *(s8v*)&hl[row*SH + lp*16 + j*8] = *(const s8v*)&lo16[j*8];
            }
        }
        __syncthreads();
        // --- GEMM1: dx = h1 @ M (3-way split), M fragments from registers ---
        #pragma unroll
        for (int mt = 0; mt < 8; ++mt) {
            s8v ah[4], al[4];
            #pragma unroll
            for (int ks = 0; ks < 4; ++ks) {
                ah[ks] = *(const s8v*)(&hs[(mt*16 + l15)*SH + ks*32 + quad*8]);
                al[ks] = *(const s8v*)(&hl[(mt*16 + l15)*SH + ks*32 + quad*8]);
            }
            f4v c = {0.f,0.f,0.f,0.f};
            #pragma unroll
            for (int ks = 0; ks < 4; ++ks) c = MFMA16(ah[ks], bh[ks], c);
            #pragma unroll
            for (int ks = 0; ks < 4; ++ks) c = MFMA16(ah[ks], bl[ks], c);
            #pragma unroll
            for (int ks = 0; ks < 4; ++ks) c = MFMA16(al[ks], bh[ks], c);
            #pragma unroll
            for (int rg = 0; rg < 4; ++rg)
                xb[(mt*16 + quad*4 + rg)*132 + cg] += c[rg];
        }
        __syncthreads();
        // --- LN2 (hi only), 2 passes ---
        #pragma unroll
        for (int pp = 0; pp < 2; ++pp) {
            const int row = pp*64 + myrow;
            float v[16];
            #pragma unroll
            for (int j = 0; j < 4; ++j)
                *(float4*)&v[j*4] = *(const float4*)&xb[row*132 + lp*16 + j*4];
            float s = 0.f, q = 0.f;
            #pragma unroll
            for (int i = 0; i < 16; ++i) { s += v[i]; q += v[i]*v[i]; }
            #pragma unroll
            for (int o = 8; o < 64; o <<= 1) { s += __shfl_xor(s, o); q += __shfl_xor(q, o); }
            const float m  = s * (1.0f/128.0f);
            const float rs = rsqrtf(q * (1.0f/128.0f) - m*m + 1e-5f);
            unsigned short hi16[16];
            #pragma unroll
            for (int j = 0; j < 4; ++j) {
                const float4 g = *(const float4*)(g2a + lp*16 + j*4);
                const float4 b = *(const float4*)(b2a + lp*16 + j*4);
                hi16[j*4+0] = f2bf((v[j*4+0]-m)*rs*g.x + b.x);
                hi16[j*4+1] = f2bf((v[j*4+1]-m)*rs*g.y + b.y);
                hi16[j*4+2] = f2bf((v[j*4+2]-m)*rs*g.z + b.z);
                hi16[j*4+3] = f2bf((v[j*4+3]-m)*rs*g.w + b.w);
            }
            #pragma unroll
            for (int j = 0; j < 2; ++j)
                *(s8v*)&hs[row*SH + lp*16 + j*8] = *(const s8v*)&hi16[j*8];
        }
        __syncthreads();
        // --- FF: 4 quarters; ALL weights from pinned registers ---
        f4v dx2[8];
        #pragma unroll
        for (int i = 0; i < 8; ++i) dx2[i] = (f4v){0.f,0.f,0.f,0.f};
        #pragma unroll
        for (int qf = 0; qf < 4; ++qf) {
            const float bias = b1r[qf];
            #pragma unroll
            for (int mt = 0; mt < 8; ++mt) {
                s8v af[4];
                #pragma unroll
                for (int ks = 0; ks < 4; ++ks)
                    af[ks] = *(const s8v*)(&hs[(mt*16 + l15)*SH + ks*32 + quad*8]);
                f4v c = {0.f,0.f,0.f,0.f};
                #pragma unroll
                for (int ks = 0; ks < 4; ++ks) c = MFMA16(af[ks], wa[qf][ks], c);
                #pragma unroll
                for (int rg = 0; rg < 4; ++rg) {
                    float vv = c[rg] + bias;
                    vv = vv > 0.f ? vv : 0.f;
                    fbuf[(mt*16 + quad*4 + rg)*SH + cg] = f2bf(vv);
                }
            }
            __syncthreads();
            #pragma unroll
            for (int mt = 0; mt < 8; ++mt) {
                s8v af[4];
                #pragma unroll
                for (int ks = 0; ks < 4; ++ks)
                    af[ks] = *(const s8v*)(&fbuf[(mt*16 + l15)*SH + ks*32 + quad*8]);
                f4v c = dx2[mt];
                #pragma unroll
                for (int ks = 0; ks < 4; ++ks) c = MFMA16(af[ks], wb[qf][ks], c);
                dx2[mt] = c;
            }
            __syncthreads();
        }
        // --- epilogue: xb += dx2 + b2 ---
        {
            const float bias = fb2[cg];
            #pragma unroll
            for (int mt = 0; mt < 8; ++mt)
                #pragma unroll
                for (int rg = 0; rg < 4; ++rg)
                    xb[(mt*16 + quad*4 + rg)*132 + cg] += dx2[mt][rg] + bias;
        }
        __syncthreads();
        // --- coalesced non-temporal store (in-place safe) ---
        #pragma unroll
        for (int i = 0; i < 8; ++i) {
            const int idx = tid + i*512;
            const int r = idx >> 5, c = (idx & 31)*4;
            ntstore4(xout + (r0 + r)*DIM + c, *(const f4v*)&xb[r*132 + c]);
        }
        __syncthreads();
    }
}

// ---------------------------------------------------------------------------
// Final: out = x @ out_w + out_b  (split-x, in-place safe on d_out).
// 256 blocks x 8 chunks of 64 rows; Owp fragments hoisted + pinned.
// ---------------------------------------------------------------------------
#define CHUNKF 64
#define NCHUNKF 8
static_assert((long)NBLK * CHUNKF * NCHUNKF == NROWS, "kF grid mismatch");

__global__ __launch_bounds__(256, 2)
void kF(const float* __restrict__ x, const unsigned short* __restrict__ Owp,
        const float* __restrict__ ob, float* __restrict__ out)
{
    __shared__ unsigned short hh[64*SH];
    __shared__ unsigned short hl[64*SH];
    __shared__ float          xb[64*132];
    const int tid  = threadIdx.x;
    const int quad = (tid & 63) >> 4, l15 = tid & 15;
    const int wv_  = tid >> 6;

    s8v bf[2][4];
    #pragma unroll
    for (int nt = 0; nt < 2; ++nt)
        #pragma unroll
        for (int ks = 0; ks < 4; ++ks) {
            bf[nt][ks] = *(const s8v*)(Owp + (wv_*32 + nt*16 + l15)*DIM + ks*32 + quad*8);
            PIN(bf[nt][ks]);
        }

    for (int ch = 0; ch < NCHUNKF; ++ch) {
        const size_t r0 = ((size_t)blockIdx.x*NCHUNKF + ch)*CHUNKF;
        #pragma unroll
        for (int i = 0; i < 8; ++i) {
            const int idx = tid + i*256;
            const int r = idx >> 5, c = (idx & 31)*4;
            const f4v v = ntload4(x + (r0 + r)*DIM + c);
            const unsigned short h0 = f2bf(v[0]), h1 = f2bf(v[1]),
                                 h2 = f2bf(v[2]), h3 = f2bf(v[3]);
            u16x4 w4 = { h0, h1, h2, h3 };
            u16x4 l4 = { f2bf(v[0] - bf2f(h0)), f2bf(v[1] - bf2f(h1)),
                         f2bf(v[2] - bf2f(h2)), f2bf(v[3] - bf2f(h3)) };
            *(u16x4*)&hh[r*SH + c] = w4;
            *(u16x4*)&hl[r*SH + c] = l4;
        }
        __syncthreads();
        #pragma unroll
        for (int mt = 0; mt < 4; ++mt) {
            s8v ah[4], al[4];
            #pragma unroll
            for (int ks = 0; ks < 4; ++ks) {
                ah[ks] = *(const s8v*)(&hh[(mt*16 + l15)*SH + ks*32 + quad*8]);
                al[ks] = *(const s8v*)(&hl[(mt*16 + l15)*SH + ks*32 + quad*8]);
            }
            #pragma unroll
            for (int nt = 0; nt < 2; ++nt) {
                f4v c = {0.f,0.f,0.f,0.f};
                #pragma unroll
                for (int ks = 0; ks < 4; ++ks) c = MFMA16(ah[ks], bf[nt][ks], c);
                #pragma unroll
                for (int ks = 0; ks < 4; ++ks) c = MFMA16(al[ks], bf[nt][ks], c);
                const int cg = wv_*32 + nt*16 + l15;
                const float bias = ob[cg];
                #pragma unroll
                for (int rg = 0; rg < 4; ++rg)
                    xb[(mt*16 + quad*4 + rg)*132 + cg] = c[rg] + bias;
            }
        }
        __syncthreads();
        #pragma unroll
        for (int i = 0; i < 8; ++i) {
            const int idx = tid + i*256;
            const int r = idx >> 5, c = (idx & 31)*4;
            ntstore4(out + (r0 + r)*DIM + c, *(const f4v*)&xb[r*132 + c]);
        }
        __syncthreads();
    }
}

// Pack weights to bf16, transposed to B-operand-friendly [n][k] layout.
__global__ void kPack(const float* __restrict__ Kw, const float* __restrict__ Vw,
                      const float* __restrict__ Ow, const float* __restrict__ w1,
                      const float* __restrict__ w2,
                      unsigned short* __restrict__ Kwp, unsigned short* __restrict__ Vwp,
                      unsigned short* __restrict__ Owp, unsigned short* __restrict__ w1p,
                      unsigned short* __restrict__ w2p)
{
    const int t = blockIdx.x*256 + threadIdx.x;  // 147456 total
    if (t < 16384) {
        const int n = t >> 7, k = t & 127;
        Kwp[t] = f2bf(Kw[k*128 + n]);
        Vwp[t] = f2bf(Vw[k*128 + n]);
        Owp[t] = f2bf(Ow[k*128 + n]);
    } else if (t < 16384 + 65536) {
        const int u = t - 16384;
        const int n = u >> 7, k = u & 127;      // w1: [128][512] -> w1p[n<512][k<128]
        w1p[u] = f2bf(w1[k*FFD + n]);
    } else {
        const int u = t - 16384 - 65536;
        const int n = u >> 9, k = u & 511;      // w2: [512][128] -> w2p[n<128][k<512]
        w2p[u] = f2bf(w2[k*DIM + n]);
    }
}

extern "C" void kernel_launch(void* const* d_in, const int* in_sizes, int n_in,
                              void* d_out, int out_size, void* d_ws, size_t ws_size,
                              hipStream_t stream)
{
    (void)in_sizes; (void)n_in; (void)out_size; (void)ws_size;
    const float* x_in = (const float*)d_in[0];
    const float* Kw   = (const float*)d_in[1];
    const float* Qw   = (const float*)d_in[2];
    const float* Vw   = (const float*)d_in[3];
    const float* ln1g = (const float*)d_in[4];
    const float* ln1b = (const float*)d_in[5];
    const float* ln2g = (const float*)d_in[6];
    const float* ln2b = (const float*)d_in[7];
    const float* w1   = (const float*)d_in[8];
    const float* b1   = (const float*)d_in[9];
    const float* w2   = (const float*)d_in[10];
    const float* b2   = (const float*)d_in[11];
    const float* Ow   = (const float*)d_in[12];
    const float* ob   = (const float*)d_in[13];

    // Workspace (~1.5 MiB single-copy layout).
    char* p = (char*)d_ws;
    float* slots        = (float*)p;          p += (size_t)NSLOT*16384*4;
    float* ktv          = (float*)p;          p += 16384*4;
    unsigned short* Kwp = (unsigned short*)p; p += 16384*2;
    unsigned short* Vwp = (unsigned short*)p; p += 16384*2;
    unsigned short* Owp = (unsigned short*)p; p += 16384*2;
    unsigned short* w1p = (unsigned short*)p; p += 65536*2;
    unsigned short* w2p = (unsigned short*)p; p += 65536*2;
    unsigned short* Mp  = (unsigned short*)p; p += 16384*2;
    unsigned short* Ml  = (unsigned short*)p; p += 16384*2;

    float* X = (float*)d_out;   // working buffer == output buffer

    kPack<<<576, 256, 0, stream>>>(Kw, Vw, Ow, w1, w2, Kwp, Vwp, Owp, w1p, w2p);

    const float* src = x_in;
    for (int t = 0; t < TSTEPS; ++t) {
        (void)hipMemsetAsync(slots, 0, (size_t)NSLOT*16384*4, stream);
        kA<<<NBLK, 512, 0, stream>>>(src, Kwp, Vwp, ln1g, ln1b, slots);
        kReduce<<<64, 256, 0, stream>>>(slots, ktv);
        kBuildM<<<64, 256, 0, stream>>>(Qw, ktv, Mp, Ml);
        kB<<<NBLK, 512, 0, stream>>>(src, X, Mp, Ml, ln1g, ln1b, ln2g, ln2b,
                                     w1p, b1, w2p, b2);
        src = X;
    }
    kF<<<NBLK, 256, 0, stream>>>(X, Owp, ob, (float*)d_out);
}